// Round 10
// baseline (501.239 us; speedup 1.0000x reference)
//
#include <hip/hip_runtime.h>
#include <cmath>

#define BB 4
#define LL 2048
#define DD 1024
#define HH 8
#define MM (BB * LL)   // 8192 rows

struct Gammas { float lg2[8]; };
struct MMArgs { const ushort* Bt[4]; void* C[4]; void* C2[4]; int emode[4]; };
struct PrepArgs { const float* W[5]; ushort* Wt[5]; int perhead[5]; };

typedef __attribute__((ext_vector_type(8))) short bf16x8;
typedef __attribute__((ext_vector_type(4))) float f32x4;

__device__ __forceinline__ ushort f2bf(float f) {
    uint u = __builtin_bit_cast(uint, f);
    uint r = (u + 0x7fffu + ((u >> 16) & 1u)) >> 16;
    return (ushort)r;
}
__device__ __forceinline__ float bf2f(ushort h) {
    uint u = ((uint)h) << 16;
    return __builtin_bit_cast(float, u);
}
__device__ __forceinline__ void gload16(const void* g, void* l) {
    __builtin_amdgcn_global_load_lds((const __attribute__((address_space(1))) void*)g,
                                     (__attribute__((address_space(3))) void*)l, 16, 0, 0);
}

// ---------------------------------------------------------------------------
// prep: ONE launch for xpos table + X cast + all 5 weight transposes.
// blocks [0,512): tbl ; [512,8704): cast ; [8704,9984): wtrans (5 x 256).
// ---------------------------------------------------------------------------
__global__ __launch_bounds__(256) void prep_kernel(
    const float* __restrict__ X, ushort* __restrict__ Xb,
    float4* __restrict__ tbl, PrepArgs pa)
{
    __shared__ float T[64][68];
    const int blk = blockIdx.x;
    const int t = threadIdx.x;

    if (blk < 512) {
        // xpos table: tbl[l*64+i] = {cos*sc, sin*sc, cos/sc, sin/sc}
        int tid = blk * 256 + t;
        int l = tid >> 6, i = tid & 63;
        float inv = powf(10000.0f, -(float)i / 64.0f);
        float ang = (float)l * inv;
        float s = sinf(ang), c = cosf(ang);
        float base = (2.0f * (float)i + 51.2f) / 179.2f;
        float sc = powf(base, (float)l / 512.0f);
        tbl[tid] = make_float4(c * sc, s * sc, c / sc, s / sc);
        return;
    }
    if (blk < 8704) {
        int i = ((blk - 512) * 256 + t) * 4;
        float4 v = *(const float4*)&X[i];
        ushort4 o;
        o.x = f2bf(v.x); o.y = f2bf(v.y); o.z = f2bf(v.z); o.w = f2bf(v.w);
        *(ushort4*)&Xb[i] = o;
        return;
    }
    // weight transpose+cast: W[k][n] (flat or per-head) -> Wt[n][k] bf16
    const int wblk = blk - 8704;
    const int widx = wblk >> 8;              // 0..4
    const int sub = wblk & 255;
    const float* W = pa.W[widx];
    ushort* Wt = pa.Wt[widx];
    const int perhead = pa.perhead[widx];
    const int k0 = (sub >> 4) * 64, n0 = (sub & 15) * 64;
    for (int f = t; f < 64 * 16; f += 256) {
        int kk = f >> 4, s = f & 15;
        int n = n0 + s * 4;
        size_t src = perhead ? (size_t)(n >> 7) * 131072 + (size_t)(k0 + kk) * 128 + (n & 127)
                             : (size_t)(k0 + kk) * 1024 + n;
        *(float4*)&T[kk][s * 4] = *(const float4*)&W[src];
    }
    __syncthreads();
    for (int f = t; f < 64 * 8; f += 256) {
        int n = f >> 3, s = f & 7;
        __align__(16) ushort tmp[8];
        #pragma unroll
        for (int j = 0; j < 8; j++) tmp[j] = f2bf(T[s * 8 + j][n]);
        *(uint4*)&Wt[(size_t)(n0 + n) * 1024 + k0 + s * 8] = *(uint4*)tmp;
    }
}

// ---------------------------------------------------------------------------
// bf16 MFMA GEMM (proven config): 128x128 tile, BK=32, 2-phase double-
// buffered LDS, one __syncthreads per K-step. __launch_bounds__(256,4)
// keeps total regs <= 128.
// emode: 1 xpos up->bf16, 2 xpos down->bf16, 3 silu->bf16, 4 plain->fp32,
//        5 V-transposed store (Vt[b][v][l]), 6 xpos down -> row-major Kb AND
//        transposed K~t (C2).
// Transposed stores (emode 5/6) go through an LDS bounce Tb[64][136]:
// fragments written [col][row] (row fast, 16B-aligned rows, <=2-way banks),
// then stored as contiguous 256B runs per column (full 64B lines) — removes
// the 4KB-stride ushort4 scatter (~37MB write amplification, 32 scattered
// stores/thread). Two half-passes (cols 0-63, 64-127) keep Tb at 17.4KB.
// ---------------------------------------------------------------------------
__global__ __launch_bounds__(256, 4) void mm_kernel(
    const ushort* __restrict__ A, MMArgs args, const float4* __restrict__ tbl)
{
    __shared__ __align__(16) ushort As[2][128 * 32];
    __shared__ __align__(16) ushort Bs[2][128 * 32];
    __shared__ __align__(16) ushort Tb[64 * 136];   // transpose bounce
    const int t = threadIdx.x;
    const int w = t >> 6, lane = t & 63;
    const int ln = lane & 15, quad = lane >> 4;
    const int which = blockIdx.x >> 3;
    const ushort* Bt = args.Bt[which];
    void* Cv = args.C[which];
    void* Cv2 = args.C2[which];
    const int emode = args.emode[which];
    const int n0 = (blockIdx.x & 7) * 128, m0 = blockIdx.y * 128;
    const int wm = w & 1, wn = w >> 1;

    f32x4 acc[4][4];
    const f32x4 fzero = {0.f, 0.f, 0.f, 0.f};
    #pragma unroll
    for (int i = 0; i < 4; i++)
        #pragma unroll
        for (int j = 0; j < 4; j++) acc[i][j] = fzero;

    const int srow = w * 32 + (lane >> 2);
    const int scol = (lane & 3) * 8;
    const ushort* ga  = A  + (size_t)(m0 + srow) * 1024 + scol;
    const ushort* ga2 = ga + 16 * 1024;
    const ushort* gb  = Bt + (size_t)(n0 + srow) * 1024 + scol;
    const ushort* gb2 = gb + 16 * 1024;
    const int lo1 = (w * 32) * 32;
    const int lo2 = (w * 32 + 16) * 32;

    gload16(ga, &As[0][lo1]);
    gload16(ga2, &As[0][lo2]);
    gload16(gb, &Bs[0][lo1]);
    gload16(gb2, &Bs[0][lo2]);
    __syncthreads();

    for (int kt = 0; kt < 1024; kt += 32) {
        const int cur = (kt >> 5) & 1;
        if (kt < 1024 - 32) {
            const int nk = kt + 32;
            gload16(ga + nk, &As[cur ^ 1][lo1]);
            gload16(ga2 + nk, &As[cur ^ 1][lo2]);
            gload16(gb + nk, &Bs[cur ^ 1][lo1]);
            gload16(gb2 + nk, &Bs[cur ^ 1][lo2]);
        }
        bf16x8 am[4], bn[4];
        #pragma unroll
        for (int i = 0; i < 4; i++)
            am[i] = *(const bf16x8*)&As[cur][(wm * 64 + i * 16 + ln) * 32 + quad * 8];
        #pragma unroll
        for (int i = 0; i < 4; i++)
            bn[i] = *(const bf16x8*)&Bs[cur][(wn * 64 + i * 16 + ln) * 32 + quad * 8];
        #pragma unroll
        for (int mi = 0; mi < 4; mi++)
            #pragma unroll
            for (int ni = 0; ni < 4; ni++)
                acc[mi][ni] = __builtin_amdgcn_mfma_f32_16x16x32_bf16(
                    am[mi], bn[ni], acc[mi][ni], 0, 0, 0);
        __syncthreads();
    }

    // ---- row-major epilogue (emodes 1,2,3,4 and emode 6's Kb part) ----
    if (emode != 5) {
        #pragma unroll
        for (int mi = 0; mi < 4; mi++) {
            #pragma unroll
            for (int ni = 0; ni < 4; ni++) {
                const int row0 = m0 + wm * 64 + mi * 16 + quad * 4;
                const int e = wn * 64 + ni * 16 + ln;       // col within head
                const int col = n0 + e;
                #pragma unroll
                for (int r = 0; r < 4; r++) {
                    float v = acc[mi][ni][r];
                    if (emode == 1 || emode == 2 || emode == 6) {
                        float4 tt = tbl[(size_t)((row0 + r) & (LL - 1)) * 64 + (e >> 1)];
                        float cc = (emode == 1) ? tt.x : tt.z;
                        float ss = (emode == 1) ? tt.y : tt.w;
                        float partner = __shfl_xor(v, 1);
                        float rot = (e & 1) ? partner : -partner;
                        v = v * cc + rot * ss;
                    } else if (emode == 3) {
                        v = v / (1.0f + expf(-v));
                    }
                    if (emode == 4)
                        ((float*)Cv)[(size_t)(row0 + r) * 1024 + col] = v;
                    else
                        ((ushort*)Cv)[(size_t)(row0 + r) * 1024 + col] = f2bf(v);
                }
            }
        }
    }

    // ---- transposed store via LDS bounce (emode 5 -> Cv, emode 6 -> Cv2) ----
    if (emode == 5 || emode == 6) {
        ushort* DST = (emode == 5) ? (ushort*)Cv : (ushort*)Cv2;
        const int bb = m0 >> 11;
        const int l0base = m0 & (LL - 1);
        #pragma unroll
        for (int hc = 0; hc < 2; hc++) {
            __syncthreads();
            if (wn == hc) {
                #pragma unroll
                for (int mi = 0; mi < 4; mi++) {
                    #pragma unroll
                    for (int ni = 0; ni < 4; ni++) {
                        const int lc = ni * 16 + ln;              // 0..63
                        const int lr = wm * 64 + mi * 16 + quad * 4;  // 0..127
                        const int row0 = m0 + lr;
                        const int e = hc * 64 + lc;               // col within head
                        ushort4 pk;
                        #pragma unroll
                        for (int r = 0; r < 4; r++) {
                            float v = acc[mi][ni][r];
                            if (emode == 6) {
                                float4 tt = tbl[(size_t)((row0 + r) & (LL - 1)) * 64 + (e >> 1)];
                                float partner = __shfl_xor(v, 1);
                                float rot = (e & 1) ? partner : -partner;
                                v = v * tt.z + rot * tt.w;
                            }
                            ((ushort*)&pk)[r] = f2bf(v);
                        }
                        *(ushort4*)&Tb[lc * 136 + lr] = pk;
                    }
                }
            }
            __syncthreads();
            // store: thread t -> col t>>2, quarter t&3 (64B contiguous, full lines)
            const int lc = t >> 2, qq = t & 3;
            const int gcol = n0 + hc * 64 + lc;
            ushort* dstp = DST + ((size_t)(bb * 1024 + gcol)) * 2048 + l0base + qq * 32;
            #pragma unroll
            for (int j = 0; j < 4; j++)
                *(uint4*)&dstp[j * 8] = *(uint4*)&Tb[lc * 136 + qq * 32 + j * 8];
        }
    }
}

// ---------------------------------------------------------------------------
// R1: per-chunk local state L_c^T[v][d] = sum_m gamma^{63-m} K~[m][d] V[m][v],
// one block per (bh, c). MFMA over m (k=64), LDS-bounced coalesced bf16 store.
// ---------------------------------------------------------------------------
__global__ __launch_bounds__(256) void state_kernel(
    const ushort* __restrict__ Ktb, const ushort* __restrict__ Vt,
    ushort* __restrict__ Sb, Gammas gp)
{
    __shared__ __align__(16) ushort shbuf[2 * 128 * 72];   // Ktl | Vwl, reused as Lsh
    ushort* Ktl = shbuf;
    ushort* Vwl = shbuf + 128 * 72;

    const int t = threadIdx.x;
    const int w = t >> 6, lane = t & 63, ln = lane & 15, quad = lane >> 4;
    const int c = blockIdx.x, bh = blockIdx.y;
    const int b = bh >> 3, h = bh & 7;
    const float lg2 = gp.lg2[h];
    const size_t tbase = ((size_t)b * 1024 + h * 128) * 2048 + (size_t)c * 64;

    const int sr = t >> 1, soff = (t & 1) * 32;
    #pragma unroll
    for (int j = 0; j < 4; j++)
        *(uint4*)&Ktl[sr * 72 + soff + j * 8] =
            *(const uint4*)&Ktb[tbase + (size_t)sr * 2048 + soff + j * 8];
    #pragma unroll
    for (int j = 0; j < 4; j++) {
        uint4 raw = *(const uint4*)&Vt[tbase + (size_t)sr * 2048 + soff + j * 8];
        ushort* rp = (ushort*)&raw;
        __align__(16) ushort tmp[8];
        #pragma unroll
        for (int jj = 0; jj < 8; jj++) {
            int m = soff + j * 8 + jj;
            tmp[jj] = f2bf(bf2f(rp[jj]) * exp2f(lg2 * (float)(63 - m)));
        }
        *(uint4*)&Vwl[sr * 72 + soff + j * 8] = *(uint4*)tmp;
    }
    __syncthreads();

    const int wm = w & 1, wn = w >> 1;
    f32x4 acc[4][4];
    const f32x4 fzero = {0.f, 0.f, 0.f, 0.f};
    #pragma unroll
    for (int i = 0; i < 4; i++)
        #pragma unroll
        for (int j = 0; j < 4; j++) acc[i][j] = fzero;

    #pragma unroll
    for (int ks = 0; ks < 2; ks++) {
        bf16x8 am[4], bn[4];
        #pragma unroll
        for (int mi = 0; mi < 4; mi++)
            am[mi] = *(const bf16x8*)&Ktl[(wm * 64 + mi * 16 + ln) * 72 + ks * 32 + quad * 8];
        #pragma unroll
        for (int ni = 0; ni < 4; ni++)
            bn[ni] = *(const bf16x8*)&Vwl[(wn * 64 + ni * 16 + ln) * 72 + ks * 32 + quad * 8];
        #pragma unroll
        for (int mi = 0; mi < 4; mi++)
            #pragma unroll
            for (int ni = 0; ni < 4; ni++)
                acc[mi][ni] = __builtin_amdgcn_mfma_f32_16x16x32_bf16(
                    am[mi], bn[ni], acc[mi][ni], 0, 0, 0);
    }
    __syncthreads();

    ushort* Lsh = shbuf;
    #pragma unroll
    for (int mi = 0; mi < 4; mi++) {
        #pragma unroll
        for (int ni = 0; ni < 4; ni++) {
            const int d0 = wm * 64 + mi * 16 + quad * 4;
            const int v = wn * 64 + ni * 16 + ln;
            ushort4 pk;
            pk.x = f2bf(acc[mi][ni][0]); pk.y = f2bf(acc[mi][ni][1]);
            pk.z = f2bf(acc[mi][ni][2]); pk.w = f2bf(acc[mi][ni][3]);
            *(ushort4*)&Lsh[v * 136 + d0] = pk;
        }
    }
    __syncthreads();
    ushort* dst = Sb + (size_t)(bh * 32 + c) * 128 * 128;
    const int orow = t >> 1, ooff = (t & 1) * 64;
    #pragma unroll
    for (int j = 0; j < 8; j++)
        *(uint4*)&dst[(size_t)orow * 128 + ooff + j * 8] =
            *(uint4*)&Lsh[orow * 136 + ooff + j * 8];
}

// ---------------------------------------------------------------------------
// R2: in-place scan over chunks: slot c-1 <- P_c = g64*P_{c-1} + L_{c-1}.
// ---------------------------------------------------------------------------
__global__ __launch_bounds__(256) void scan_kernel(ushort* __restrict__ Sb, Gammas gp)
{
    const int t = threadIdx.x;
    const int vb = blockIdx.x, bh = blockIdx.y;
    const int h = bh & 7;
    const float g64 = exp2f(64.0f * gp.lg2[h]);
    const int v = vb * 16 + (t >> 4);
    const int d0 = (t & 15) * 8;

    float acc[8];
    #pragma unroll
    for (int j = 0; j < 8; j++) acc[j] = 0.f;

    for (int c = 1; c < 32; c++) {
        ushort* p = Sb + ((size_t)(bh * 32 + (c - 1)) * 128 + v) * 128 + d0;
        uint4 lv = *(const uint4*)p;
        ushort* lp = (ushort*)&lv;
        __align__(16) ushort o[8];
        #pragma unroll
        for (int j = 0; j < 8; j++) {
            acc[j] = g64 * acc[j] + bf2f(lp[j]);
            o[j] = f2bf(acc[j]);
        }
        *(uint4*)p = *(uint4*)o;
    }
}

// ---------------------------------------------------------------------------
// R3: Y(chunk c) = gamma^{r+1} * Q~ . P_c  +  intra-chunk retention,
// fused GroupNorm + affine + silu-gate epilogue. One block per (bh, c).
// P consumed DIRECTLY global->register; inter-chunk MFMA overlaps staging.
// ---------------------------------------------------------------------------
__global__ __launch_bounds__(256) void ret2_kernel(
    const ushort* __restrict__ Qb, const ushort* __restrict__ Kb,
    const ushort* __restrict__ Vt, const ushort* __restrict__ Pt,
    const ushort* __restrict__ Gb,
    const float* __restrict__ gnw, const float* __restrict__ gnb,
    ushort* __restrict__ Z, Gammas gp)
{
    __shared__ __align__(16) ushort Ks[64 * 136];
    __shared__ __align__(16) ushort Vs[128 * 72];
    __shared__ __align__(16) ushort Ss[64 * 72];

    const int t = threadIdx.x;
    const int w = t >> 6, lane = t & 63, ln = lane & 15, quad = lane >> 4;
    const int c = blockIdx.x, bh = blockIdx.y;
    const int b = bh >> 3, h = bh & 7;
    const float lg2 = gp.lg2[h];
    const size_t qkbase = (size_t)b * LL * 1024 + (size_t)h * 128;
    const size_t vtbase = ((size_t)b * 1024 + h * 128) * 2048;
    const int n0 = c * 64;

    float dmk[4], drr[4];
    #pragma unroll
    for (int kt = 0; kt < 4; kt++)
        dmk[kt] = exp2f(-(float)(kt * 16 + quad * 4) * lg2);
    #pragma unroll
    for (int r = 0; r < 4; r++)
        drr[r] = exp2f(-(float)r * lg2);

    float gwv[8], gbv[8];
    #pragma unroll
    for (int vt = 0; vt < 8; vt++) {
        gwv[vt] = gnw[h * 128 + vt * 16 + ln];
        gbv[vt] = gnb[h * 128 + vt * 16 + ln];
    }

    const int krow = t >> 4, kc = (t & 15) * 8;
    const int vrow = t >> 3, vc = (t & 7) * 8;
    #pragma unroll
    for (int i = 0; i < 4; i++)
        *(uint4*)&Ks[(krow + i * 16) * 136 + kc] =
            *(const uint4*)&Kb[qkbase + (size_t)(n0 + krow + i * 16) * 1024 + kc];
    #pragma unroll
    for (int i = 0; i < 4; i++)
        *(uint4*)&Vs[(vrow + i * 32) * 72 + vc] =
            *(const uint4*)&Vt[vtbase + (size_t)(vrow + i * 32) * 2048 + n0 + vc];

    bf16x8 aq[4];
    #pragma unroll
    for (int ks = 0; ks < 4; ks++)
        aq[ks] = *(const bf16x8*)&Qb[qkbase + (size_t)(n0 + 16 * w + ln) * 1024
                                     + ks * 32 + quad * 8];
    f32x4 y[8];
    const f32x4 fzero = {0.f, 0.f, 0.f, 0.f};
    #pragma unroll
    for (int vt = 0; vt < 8; vt++) y[vt] = fzero;

    // inter-chunk: y = Q~ . P_c with P fragments loaded straight from global
    if (c > 0) {
        const ushort* psrc = Pt + (size_t)(bh * 32 + (c - 1)) * 128 * 128;
        #pragma unroll
        for (int ks = 0; ks < 4; ks++) {
            bf16x8 bp[8];
            #pragma unroll
            for (int vt = 0; vt < 8; vt++)
                bp[vt] = *(const bf16x8*)&psrc[(size_t)(vt * 16 + ln) * 128
                                               + ks * 32 + quad * 8];
            #pragma unroll
            for (int vt = 0; vt < 8; vt++)
                y[vt] = __builtin_amdgcn_mfma_f32_16x16x32_bf16(aq[ks], bp[vt], y[vt], 0, 0, 0);
        }
        #pragma unroll
        for (int rr = 0; rr < 4; rr++) {
            const float sc = exp2f(lg2 * (float)(16 * w + quad * 4 + rr + 1));
            #pragma unroll
            for (int vt = 0; vt < 8; vt++) y[vt][rr] *= sc;
        }
    }

    __syncthreads();

    f32x4 s4[4];
    #pragma unroll
    for (int kt = 0; kt < 4; kt++) s4[kt] = fzero;
    #pragma unroll
    for (int ks = 0; ks < 4; ks++) {
        #pragma unroll
        for (int kt = 0; kt < 4; kt++) {
            bf16x8 bk = *(const bf16x8*)&Ks[(kt * 16 + ln) * 136 + ks * 32 + quad * 8];
            s4[kt] = __builtin_amdgcn_mfma_f32_16x16x32_bf16(bk, aq[ks], s4[kt], 0, 0, 0);
        }
    }
    const float dq = exp2f((float)(16 * w + ln) * lg2);
    #pragma unroll
    for (int kt = 0; kt < 4; kt++) {
        const float db = dq * dmk[kt];
        ushort4 pk;
        pk.x = f2bf((kt * 16 + quad * 4 + 0 <= 16 * w + ln) ? s4[kt][0] * db * drr[0] : 0.f);
        pk.y = f2bf((kt * 16 + quad * 4 + 1 <= 16 * w + ln) ? s4[kt][1] * db * drr[1] : 0.f);
        pk.z = f2bf((kt * 16 + quad * 4 + 2 <= 16 * w + ln) ? s4[kt][2] * db * drr[2] : 0.f);
        pk.w = f2bf((kt * 16 + quad * 4 + 3 <= 16 * w + ln) ? s4[kt][3] * db * drr[3] : 0.f);
        *(ushort4*)&Ss[(16 * w + ln) * 72 + kt * 16 + quad * 4] = pk;
    }
    #pragma unroll
    for (int ks2 = 0; ks2 < 2; ks2++) {
        bf16x8 as = *(const bf16x8*)&Ss[(16 * w + ln) * 72 + ks2 * 32 + quad * 8];
        #pragma unroll
        for (int vt = 0; vt < 8; vt++) {
            bf16x8 bv = *(const bf16x8*)&Vs[(vt * 16 + ln) * 72 + ks2 * 32 + quad * 8];
            y[vt] = __builtin_amdgcn_mfma_f32_16x16x32_bf16(as, bv, y[vt], 0, 0, 0);
        }
    }

    #pragma unroll
    for (int r = 0; r < 4; r++) {
        float s = 0.f, sq = 0.f;
        #pragma unroll
        for (int vt = 0; vt < 8; vt++) {
            float v = y[vt][r];
            s += v; sq += v * v;
        }
        #pragma unroll
        for (int off = 8; off >= 1; off >>= 1) {
            s  += __shfl_xor(s, off, 64);
            sq += __shfl_xor(sq, off, 64);
        }
        float mean = s * 0.0078125f;
        float var = sq * 0.0078125f - mean * mean;
        float rstd = rsqrtf(var + 1e-5f);
        const size_t row = (size_t)(b * LL + n0 + 16 * w + quad * 4 + r);
        #pragma unroll
        for (int vt = 0; vt < 8; vt++) {
            float gv = bf2f(Gb[row * 1024 + h * 128 + vt * 16 + ln]);
            float o = (y[vt][r] - mean) * rstd * gwv[vt] + gbv[vt];
            Z[row * 1024 + h * 128 + vt * 16 + ln] = f2bf(o * gv);
        }
    }
}

// ---------------------------------------------------------------------------
extern "C" void kernel_launch(void* const* d_in, const int* in_sizes, int n_in,
                              void* d_out, int out_size, void* d_ws, size_t ws_size,
                              hipStream_t stream) {
    const float* X   = (const float*)d_in[0];
    const float* Wq  = (const float*)d_in[1];
    const float* Wk  = (const float*)d_in[2];
    const float* Wv  = (const float*)d_in[3];
    const float* Wg  = (const float*)d_in[4];
    const float* Wo  = (const float*)d_in[5];
    const float* gnw = (const float*)d_in[6];
    const float* gnb = (const float*)d_in[7];
    float* out = (float*)d_out;

    const size_t MB = 1u << 20;
    char* base = (char*)d_ws;
    // Sb (32 MB, 0-32) overlays tbl/Xb/Wq..Wg, which die after the QKVG mm.
    ushort* Sb  = (ushort*)base;                        // 0-32  (L then P, bf16)
    float4* tbl = (float4*)base;                        // 0-2
    ushort* Xb  = (ushort*)(base + 2 * MB);             // 2-18
    ushort* Wqt = (ushort*)(base + 18 * MB);
    ushort* Wkt = (ushort*)(base + 20 * MB);
    ushort* Wvt = (ushort*)(base + 22 * MB);
    ushort* Wgt = (ushort*)(base + 24 * MB);
    ushort* Wot = (ushort*)(base + 32 * MB);            // 32-34
    ushort* Qb  = (ushort*)(base + 34 * MB);            // 34-50
    ushort* Kb  = (ushort*)(base + 50 * MB);            // 50-66
    ushort* Gb  = (ushort*)(base + 66 * MB);            // 66-82
    ushort* Vt  = (ushort*)(base + 82 * MB);            // 82-98
    ushort* Ktb = (ushort*)(base + 98 * MB);            // 98-114 (dead after R1)
    ushort* Zb  = (ushort*)(base + 98 * MB);            // reuses Ktb region in R3+

    Gammas gp;
    for (int h = 0; h < 8; h++) {
        double lin = log(1.0 / 32.0) +
                     (log(1.0 / 512.0) - log(1.0 / 32.0)) * (double)h / 7.0;
        float gamma = 1.0f - expf((float)lin);
        gp.lg2[h] = log2f(gamma);
    }

    // single prep launch: xpos table + cast + all 5 weight transposes
    PrepArgs pa;
    pa.W[0] = Wq;  pa.Wt[0] = Wqt; pa.perhead[0] = 1;
    pa.W[1] = Wk;  pa.Wt[1] = Wkt; pa.perhead[1] = 1;
    pa.W[2] = Wv;  pa.Wt[2] = Wvt; pa.perhead[2] = 1;
    pa.W[3] = Wg;  pa.Wt[3] = Wgt; pa.perhead[3] = 0;
    pa.W[4] = Wo;  pa.Wt[4] = Wot; pa.perhead[4] = 0;
    prep_kernel<<<9984, 256, 0, stream>>>(X, Xb, tbl, pa);

    // fused Q/K/V/G projections; K emits row-major Kb AND transposed K~t
    MMArgs qa;
    qa.Bt[0] = Wqt; qa.Bt[1] = Wkt; qa.Bt[2] = Wvt; qa.Bt[3] = Wgt;
    qa.C[0] = Qb;   qa.C[1] = Kb;   qa.C[2] = Vt;   qa.C[3] = Gb;
    qa.C2[0] = nullptr; qa.C2[1] = Ktb; qa.C2[2] = nullptr; qa.C2[3] = nullptr;
    qa.emode[0] = 1; qa.emode[1] = 6; qa.emode[2] = 5; qa.emode[3] = 3;
    mm_kernel<<<dim3(32, 64), 256, 0, stream>>>(Xb, qa, tbl);

    // chunked-recurrent retention: local states -> scan -> per-chunk output
    state_kernel<<<dim3(32, 32), 256, 0, stream>>>(Ktb, Vt, Sb, gp);
    scan_kernel<<<dim3(8, 32), 256, 0, stream>>>(Sb, gp);
    ret2_kernel<<<dim3(32, 32), 256, 0, stream>>>(Qb, Kb, Vt, Sb, Gb,
                                                  gnw, gnb, Zb, gp);

    MMArgs oa;
    oa.Bt[0] = Wot; oa.Bt[1] = Wot; oa.Bt[2] = Wot; oa.Bt[3] = Wot;
    oa.C[0] = out;  oa.C[1] = out;  oa.C[2] = out;  oa.C[3] = out;
    oa.C2[0] = nullptr; oa.C2[1] = nullptr; oa.C2[2] = nullptr; oa.C2[3] = nullptr;
    oa.emode[0] = 4; oa.emode[1] = 4; oa.emode[2] = 4; oa.emode[3] = 4;
    mm_kernel<<<dim3(8, 64), 256, 0, stream>>>(Zb, oa, tbl);
}

// Round 11
// 345.157 us; speedup vs baseline: 1.4522x; 1.4522x over previous
//
#include <hip/hip_runtime.h>
#include <cmath>

#define BB 4
#define LL 2048
#define DD 1024
#define HH 8
#define MM (BB * LL)   // 8192 rows

struct Gammas { float lg2[8]; };
struct MMArgs { const ushort* Bt[4]; void* C[4]; void* C2[4]; int emode[4]; };
struct PrepArgs { const float* W[5]; ushort* Wt[5]; int perhead[5]; };

typedef __attribute__((ext_vector_type(8))) short bf16x8;
typedef __attribute__((ext_vector_type(4))) float f32x4;

__device__ __forceinline__ ushort f2bf(float f) {
    uint u = __builtin_bit_cast(uint, f);
    uint r = (u + 0x7fffu + ((u >> 16) & 1u)) >> 16;
    return (ushort)r;
}
__device__ __forceinline__ float bf2f(ushort h) {
    uint u = ((uint)h) << 16;
    return __builtin_bit_cast(float, u);
}
__device__ __forceinline__ void gload16(const void* g, void* l) {
    __builtin_amdgcn_global_load_lds((const __attribute__((address_space(1))) void*)g,
                                     (__attribute__((address_space(3))) void*)l, 16, 0, 0);
}

// ---------------------------------------------------------------------------
// prep: ONE launch for xpos table + X cast + all 5 weight transposes.
// blocks [0,512): tbl ; [512,8704): cast ; [8704,9984): wtrans (5 x 256).
// ---------------------------------------------------------------------------
__global__ __launch_bounds__(256) void prep_kernel(
    const float* __restrict__ X, ushort* __restrict__ Xb,
    float4* __restrict__ tbl, PrepArgs pa)
{
    __shared__ float T[64][68];
    const int blk = blockIdx.x;
    const int t = threadIdx.x;

    if (blk < 512) {
        // xpos table: tbl[l*64+i] = {cos*sc, sin*sc, cos/sc, sin/sc}
        int tid = blk * 256 + t;
        int l = tid >> 6, i = tid & 63;
        float inv = powf(10000.0f, -(float)i / 64.0f);
        float ang = (float)l * inv;
        float s = sinf(ang), c = cosf(ang);
        float base = (2.0f * (float)i + 51.2f) / 179.2f;
        float sc = powf(base, (float)l / 512.0f);
        tbl[tid] = make_float4(c * sc, s * sc, c / sc, s / sc);
        return;
    }
    if (blk < 8704) {
        int i = ((blk - 512) * 256 + t) * 4;
        float4 v = *(const float4*)&X[i];
        ushort4 o;
        o.x = f2bf(v.x); o.y = f2bf(v.y); o.z = f2bf(v.z); o.w = f2bf(v.w);
        *(ushort4*)&Xb[i] = o;
        return;
    }
    // weight transpose+cast: W[k][n] (flat or per-head) -> Wt[n][k] bf16
    const int wblk = blk - 8704;
    const int widx = wblk >> 8;              // 0..4
    const int sub = wblk & 255;
    const float* W = pa.W[widx];
    ushort* Wt = pa.Wt[widx];
    const int perhead = pa.perhead[widx];
    const int k0 = (sub >> 4) * 64, n0 = (sub & 15) * 64;
    for (int f = t; f < 64 * 16; f += 256) {
        int kk = f >> 4, s = f & 15;
        int n = n0 + s * 4;
        size_t src = perhead ? (size_t)(n >> 7) * 131072 + (size_t)(k0 + kk) * 128 + (n & 127)
                             : (size_t)(k0 + kk) * 1024 + n;
        *(float4*)&T[kk][s * 4] = *(const float4*)&W[src];
    }
    __syncthreads();
    for (int f = t; f < 64 * 8; f += 256) {
        int n = f >> 3, s = f & 7;
        __align__(16) ushort tmp[8];
        #pragma unroll
        for (int j = 0; j < 8; j++) tmp[j] = f2bf(T[s * 8 + j][n]);
        *(uint4*)&Wt[(size_t)(n0 + n) * 1024 + k0 + s * 8] = *(uint4*)tmp;
    }
}

// ---------------------------------------------------------------------------
// bf16 MFMA GEMM (proven config): 128x128 tile, BK=32, 2-phase double-
// buffered LDS, one __syncthreads per K-step. __launch_bounds__(256,4)
// keeps total regs <= 128 (4 blocks/CU; LDS 32KB x 4 = 128KB).
// NOTE (round-10 lesson): transposed scatter stores (emode 5/6) are fully
// hidden under the K-loop — an LDS-bounce "fix" dropped WRITE_SIZE 119->82MB
// but regressed dur 181->300us (VGPR 64->96, LDS 50KB -> 3 blocks/CU,
// epilogue barriers). Keep the scatter.
// emode: 1 xpos up->bf16, 2 xpos down->bf16, 3 silu->bf16, 4 plain->fp32,
//        5 V-transposed store (Vt[b][v][l]), 6 xpos down -> row-major Kb AND
//        transposed K~t (C2).
// ---------------------------------------------------------------------------
__global__ __launch_bounds__(256, 4) void mm_kernel(
    const ushort* __restrict__ A, MMArgs args, const float4* __restrict__ tbl)
{
    __shared__ __align__(16) ushort As[2][128 * 32];
    __shared__ __align__(16) ushort Bs[2][128 * 32];
    const int t = threadIdx.x;
    const int w = t >> 6, lane = t & 63;
    const int ln = lane & 15, quad = lane >> 4;
    const int which = blockIdx.x >> 3;
    const ushort* Bt = args.Bt[which];
    void* Cv = args.C[which];
    void* Cv2 = args.C2[which];
    const int emode = args.emode[which];
    const int n0 = (blockIdx.x & 7) * 128, m0 = blockIdx.y * 128;
    const int wm = w & 1, wn = w >> 1;

    f32x4 acc[4][4];
    const f32x4 fzero = {0.f, 0.f, 0.f, 0.f};
    #pragma unroll
    for (int i = 0; i < 4; i++)
        #pragma unroll
        for (int j = 0; j < 4; j++) acc[i][j] = fzero;

    const int srow = w * 32 + (lane >> 2);
    const int scol = (lane & 3) * 8;
    const ushort* ga  = A  + (size_t)(m0 + srow) * 1024 + scol;
    const ushort* ga2 = ga + 16 * 1024;
    const ushort* gb  = Bt + (size_t)(n0 + srow) * 1024 + scol;
    const ushort* gb2 = gb + 16 * 1024;
    const int lo1 = (w * 32) * 32;
    const int lo2 = (w * 32 + 16) * 32;

    gload16(ga, &As[0][lo1]);
    gload16(ga2, &As[0][lo2]);
    gload16(gb, &Bs[0][lo1]);
    gload16(gb2, &Bs[0][lo2]);
    __syncthreads();

    for (int kt = 0; kt < 1024; kt += 32) {
        const int cur = (kt >> 5) & 1;
        if (kt < 1024 - 32) {
            const int nk = kt + 32;
            gload16(ga + nk, &As[cur ^ 1][lo1]);
            gload16(ga2 + nk, &As[cur ^ 1][lo2]);
            gload16(gb + nk, &Bs[cur ^ 1][lo1]);
            gload16(gb2 + nk, &Bs[cur ^ 1][lo2]);
        }
        bf16x8 am[4], bn[4];
        #pragma unroll
        for (int i = 0; i < 4; i++)
            am[i] = *(const bf16x8*)&As[cur][(wm * 64 + i * 16 + ln) * 32 + quad * 8];
        #pragma unroll
        for (int i = 0; i < 4; i++)
            bn[i] = *(const bf16x8*)&Bs[cur][(wn * 64 + i * 16 + ln) * 32 + quad * 8];
        #pragma unroll
        for (int mi = 0; mi < 4; mi++)
            #pragma unroll
            for (int ni = 0; ni < 4; ni++)
                acc[mi][ni] = __builtin_amdgcn_mfma_f32_16x16x32_bf16(
                    am[mi], bn[ni], acc[mi][ni], 0, 0, 0);
        __syncthreads();
    }

    #pragma unroll
    for (int mi = 0; mi < 4; mi++) {
        #pragma unroll
        for (int ni = 0; ni < 4; ni++) {
            const int row0 = m0 + wm * 64 + mi * 16 + quad * 4;
            const int e = wn * 64 + ni * 16 + ln;       // col within head
            const int col = n0 + e;
            if (emode == 5) {
                const int b = row0 >> 11, l0 = row0 & (LL - 1);
                ushort4 pk;
                pk.x = f2bf(acc[mi][ni][0]); pk.y = f2bf(acc[mi][ni][1]);
                pk.z = f2bf(acc[mi][ni][2]); pk.w = f2bf(acc[mi][ni][3]);
                *(ushort4*)&((ushort*)Cv)[((size_t)(b * 1024 + col)) * 2048 + l0] = pk;
                continue;
            }
            float vv[4];
            #pragma unroll
            for (int r = 0; r < 4; r++) {
                float v = acc[mi][ni][r];
                if (emode == 1 || emode == 2 || emode == 6) {
                    float4 tt = tbl[(size_t)((row0 + r) & (LL - 1)) * 64 + (e >> 1)];
                    float cc = (emode == 1) ? tt.x : tt.z;
                    float ss = (emode == 1) ? tt.y : tt.w;
                    float partner = __shfl_xor(v, 1);
                    float rot = (e & 1) ? partner : -partner;
                    v = v * cc + rot * ss;
                } else if (emode == 3) {
                    v = v / (1.0f + expf(-v));
                }
                vv[r] = v;
                if (emode == 4)
                    ((float*)Cv)[(size_t)(row0 + r) * 1024 + col] = v;
                else
                    ((ushort*)Cv)[(size_t)(row0 + r) * 1024 + col] = f2bf(v);
            }
            if (emode == 6) {
                const int b = row0 >> 11, l0 = row0 & (LL - 1);
                ushort4 pk;
                pk.x = f2bf(vv[0]); pk.y = f2bf(vv[1]);
                pk.z = f2bf(vv[2]); pk.w = f2bf(vv[3]);
                *(ushort4*)&((ushort*)Cv2)[((size_t)(b * 1024 + col)) * 2048 + l0] = pk;
            }
        }
    }
}

// ---------------------------------------------------------------------------
// R1: per-chunk local state L_c^T[v][d] = sum_m gamma^{63-m} K~[m][d] V[m][v],
// one block per (bh, c). MFMA over m (k=64), LDS-bounced coalesced bf16 store.
// ---------------------------------------------------------------------------
__global__ __launch_bounds__(256) void state_kernel(
    const ushort* __restrict__ Ktb, const ushort* __restrict__ Vt,
    ushort* __restrict__ Sb, Gammas gp)
{
    __shared__ __align__(16) ushort shbuf[2 * 128 * 72];   // Ktl | Vwl, reused as Lsh
    ushort* Ktl = shbuf;
    ushort* Vwl = shbuf + 128 * 72;

    const int t = threadIdx.x;
    const int w = t >> 6, lane = t & 63, ln = lane & 15, quad = lane >> 4;
    const int c = blockIdx.x, bh = blockIdx.y;
    const int b = bh >> 3, h = bh & 7;
    const float lg2 = gp.lg2[h];
    const size_t tbase = ((size_t)b * 1024 + h * 128) * 2048 + (size_t)c * 64;

    const int sr = t >> 1, soff = (t & 1) * 32;
    #pragma unroll
    for (int j = 0; j < 4; j++)
        *(uint4*)&Ktl[sr * 72 + soff + j * 8] =
            *(const uint4*)&Ktb[tbase + (size_t)sr * 2048 + soff + j * 8];
    #pragma unroll
    for (int j = 0; j < 4; j++) {
        uint4 raw = *(const uint4*)&Vt[tbase + (size_t)sr * 2048 + soff + j * 8];
        ushort* rp = (ushort*)&raw;
        __align__(16) ushort tmp[8];
        #pragma unroll
        for (int jj = 0; jj < 8; jj++) {
            int m = soff + j * 8 + jj;
            tmp[jj] = f2bf(bf2f(rp[jj]) * exp2f(lg2 * (float)(63 - m)));
        }
        *(uint4*)&Vwl[sr * 72 + soff + j * 8] = *(uint4*)tmp;
    }
    __syncthreads();

    const int wm = w & 1, wn = w >> 1;
    f32x4 acc[4][4];
    const f32x4 fzero = {0.f, 0.f, 0.f, 0.f};
    #pragma unroll
    for (int i = 0; i < 4; i++)
        #pragma unroll
        for (int j = 0; j < 4; j++) acc[i][j] = fzero;

    #pragma unroll
    for (int ks = 0; ks < 2; ks++) {
        bf16x8 am[4], bn[4];
        #pragma unroll
        for (int mi = 0; mi < 4; mi++)
            am[mi] = *(const bf16x8*)&Ktl[(wm * 64 + mi * 16 + ln) * 72 + ks * 32 + quad * 8];
        #pragma unroll
        for (int ni = 0; ni < 4; ni++)
            bn[ni] = *(const bf16x8*)&Vwl[(wn * 64 + ni * 16 + ln) * 72 + ks * 32 + quad * 8];
        #pragma unroll
        for (int mi = 0; mi < 4; mi++)
            #pragma unroll
            for (int ni = 0; ni < 4; ni++)
                acc[mi][ni] = __builtin_amdgcn_mfma_f32_16x16x32_bf16(
                    am[mi], bn[ni], acc[mi][ni], 0, 0, 0);
    }
    __syncthreads();

    ushort* Lsh = shbuf;
    #pragma unroll
    for (int mi = 0; mi < 4; mi++) {
        #pragma unroll
        for (int ni = 0; ni < 4; ni++) {
            const int d0 = wm * 64 + mi * 16 + quad * 4;
            const int v = wn * 64 + ni * 16 + ln;
            ushort4 pk;
            pk.x = f2bf(acc[mi][ni][0]); pk.y = f2bf(acc[mi][ni][1]);
            pk.z = f2bf(acc[mi][ni][2]); pk.w = f2bf(acc[mi][ni][3]);
            *(ushort4*)&Lsh[v * 136 + d0] = pk;
        }
    }
    __syncthreads();
    ushort* dst = Sb + (size_t)(bh * 32 + c) * 128 * 128;
    const int orow = t >> 1, ooff = (t & 1) * 64;
    #pragma unroll
    for (int j = 0; j < 8; j++)
        *(uint4*)&dst[(size_t)orow * 128 + ooff + j * 8] =
            *(uint4*)&Lsh[orow * 136 + ooff + j * 8];
}

// ---------------------------------------------------------------------------
// R2: in-place scan over chunks: slot c-1 <- P_c = g64*P_{c-1} + L_{c-1}.
// ---------------------------------------------------------------------------
__global__ __launch_bounds__(256) void scan_kernel(ushort* __restrict__ Sb, Gammas gp)
{
    const int t = threadIdx.x;
    const int vb = blockIdx.x, bh = blockIdx.y;
    const int h = bh & 7;
    const float g64 = exp2f(64.0f * gp.lg2[h]);
    const int v = vb * 16 + (t >> 4);
    const int d0 = (t & 15) * 8;

    float acc[8];
    #pragma unroll
    for (int j = 0; j < 8; j++) acc[j] = 0.f;

    for (int c = 1; c < 32; c++) {
        ushort* p = Sb + ((size_t)(bh * 32 + (c - 1)) * 128 + v) * 128 + d0;
        uint4 lv = *(const uint4*)p;
        ushort* lp = (ushort*)&lv;
        __align__(16) ushort o[8];
        #pragma unroll
        for (int j = 0; j < 8; j++) {
            acc[j] = g64 * acc[j] + bf2f(lp[j]);
            o[j] = f2bf(acc[j]);
        }
        *(uint4*)p = *(uint4*)o;
    }
}

// ---------------------------------------------------------------------------
// R3: Y(chunk c) = gamma^{r+1} * Q~ . P_c  +  intra-chunk retention,
// fused GroupNorm + affine + silu-gate epilogue. One block per (bh, c).
// P consumed DIRECTLY global->register; inter-chunk MFMA overlaps staging.
// ---------------------------------------------------------------------------
__global__ __launch_bounds__(256) void ret2_kernel(
    const ushort* __restrict__ Qb, const ushort* __restrict__ Kb,
    const ushort* __restrict__ Vt, const ushort* __restrict__ Pt,
    const ushort* __restrict__ Gb,
    const float* __restrict__ gnw, const float* __restrict__ gnb,
    ushort* __restrict__ Z, Gammas gp)
{
    __shared__ __align__(16) ushort Ks[64 * 136];
    __shared__ __align__(16) ushort Vs[128 * 72];
    __shared__ __align__(16) ushort Ss[64 * 72];

    const int t = threadIdx.x;
    const int w = t >> 6, lane = t & 63, ln = lane & 15, quad = lane >> 4;
    const int c = blockIdx.x, bh = blockIdx.y;
    const int b = bh >> 3, h = bh & 7;
    const float lg2 = gp.lg2[h];
    const size_t qkbase = (size_t)b * LL * 1024 + (size_t)h * 128;
    const size_t vtbase = ((size_t)b * 1024 + h * 128) * 2048;
    const int n0 = c * 64;

    float dmk[4], drr[4];
    #pragma unroll
    for (int kt = 0; kt < 4; kt++)
        dmk[kt] = exp2f(-(float)(kt * 16 + quad * 4) * lg2);
    #pragma unroll
    for (int r = 0; r < 4; r++)
        drr[r] = exp2f(-(float)r * lg2);

    float gwv[8], gbv[8];
    #pragma unroll
    for (int vt = 0; vt < 8; vt++) {
        gwv[vt] = gnw[h * 128 + vt * 16 + ln];
        gbv[vt] = gnb[h * 128 + vt * 16 + ln];
    }

    const int krow = t >> 4, kc = (t & 15) * 8;
    const int vrow = t >> 3, vc = (t & 7) * 8;
    #pragma unroll
    for (int i = 0; i < 4; i++)
        *(uint4*)&Ks[(krow + i * 16) * 136 + kc] =
            *(const uint4*)&Kb[qkbase + (size_t)(n0 + krow + i * 16) * 1024 + kc];
    #pragma unroll
    for (int i = 0; i < 4; i++)
        *(uint4*)&Vs[(vrow + i * 32) * 72 + vc] =
            *(const uint4*)&Vt[vtbase + (size_t)(vrow + i * 32) * 2048 + n0 + vc];

    bf16x8 aq[4];
    #pragma unroll
    for (int ks = 0; ks < 4; ks++)
        aq[ks] = *(const bf16x8*)&Qb[qkbase + (size_t)(n0 + 16 * w + ln) * 1024
                                     + ks * 32 + quad * 8];
    f32x4 y[8];
    const f32x4 fzero = {0.f, 0.f, 0.f, 0.f};
    #pragma unroll
    for (int vt = 0; vt < 8; vt++) y[vt] = fzero;

    // inter-chunk: y = Q~ . P_c with P fragments loaded straight from global
    if (c > 0) {
        const ushort* psrc = Pt + (size_t)(bh * 32 + (c - 1)) * 128 * 128;
        #pragma unroll
        for (int ks = 0; ks < 4; ks++) {
            bf16x8 bp[8];
            #pragma unroll
            for (int vt = 0; vt < 8; vt++)
                bp[vt] = *(const bf16x8*)&psrc[(size_t)(vt * 16 + ln) * 128
                                               + ks * 32 + quad * 8];
            #pragma unroll
            for (int vt = 0; vt < 8; vt++)
                y[vt] = __builtin_amdgcn_mfma_f32_16x16x32_bf16(aq[ks], bp[vt], y[vt], 0, 0, 0);
        }
        #pragma unroll
        for (int rr = 0; rr < 4; rr++) {
            const float sc = exp2f(lg2 * (float)(16 * w + quad * 4 + rr + 1));
            #pragma unroll
            for (int vt = 0; vt < 8; vt++) y[vt][rr] *= sc;
        }
    }

    __syncthreads();

    f32x4 s4[4];
    #pragma unroll
    for (int kt = 0; kt < 4; kt++) s4[kt] = fzero;
    #pragma unroll
    for (int ks = 0; ks < 4; ks++) {
        #pragma unroll
        for (int kt = 0; kt < 4; kt++) {
            bf16x8 bk = *(const bf16x8*)&Ks[(kt * 16 + ln) * 136 + ks * 32 + quad * 8];
            s4[kt] = __builtin_amdgcn_mfma_f32_16x16x32_bf16(bk, aq[ks], s4[kt], 0, 0, 0);
        }
    }
    const float dq = exp2f((float)(16 * w + ln) * lg2);
    #pragma unroll
    for (int kt = 0; kt < 4; kt++) {
        const float db = dq * dmk[kt];
        ushort4 pk;
        pk.x = f2bf((kt * 16 + quad * 4 + 0 <= 16 * w + ln) ? s4[kt][0] * db * drr[0] : 0.f);
        pk.y = f2bf((kt * 16 + quad * 4 + 1 <= 16 * w + ln) ? s4[kt][1] * db * drr[1] : 0.f);
        pk.z = f2bf((kt * 16 + quad * 4 + 2 <= 16 * w + ln) ? s4[kt][2] * db * drr[2] : 0.f);
        pk.w = f2bf((kt * 16 + quad * 4 + 3 <= 16 * w + ln) ? s4[kt][3] * db * drr[3] : 0.f);
        *(ushort4*)&Ss[(16 * w + ln) * 72 + kt * 16 + quad * 4] = pk;
    }
    #pragma unroll
    for (int ks2 = 0; ks2 < 2; ks2++) {
        bf16x8 as = *(const bf16x8*)&Ss[(16 * w + ln) * 72 + ks2 * 32 + quad * 8];
        #pragma unroll
        for (int vt = 0; vt < 8; vt++) {
            bf16x8 bv = *(const bf16x8*)&Vs[(vt * 16 + ln) * 72 + ks2 * 32 + quad * 8];
            y[vt] = __builtin_amdgcn_mfma_f32_16x16x32_bf16(as, bv, y[vt], 0, 0, 0);
        }
    }

    #pragma unroll
    for (int r = 0; r < 4; r++) {
        float s = 0.f, sq = 0.f;
        #pragma unroll
        for (int vt = 0; vt < 8; vt++) {
            float v = y[vt][r];
            s += v; sq += v * v;
        }
        #pragma unroll
        for (int off = 8; off >= 1; off >>= 1) {
            s  += __shfl_xor(s, off, 64);
            sq += __shfl_xor(sq, off, 64);
        }
        float mean = s * 0.0078125f;
        float var = sq * 0.0078125f - mean * mean;
        float rstd = rsqrtf(var + 1e-5f);
        const size_t row = (size_t)(b * LL + n0 + 16 * w + quad * 4 + r);
        #pragma unroll
        for (int vt = 0; vt < 8; vt++) {
            float gv = bf2f(Gb[row * 1024 + h * 128 + vt * 16 + ln]);
            float o = (y[vt][r] - mean) * rstd * gwv[vt] + gbv[vt];
            Z[row * 1024 + h * 128 + vt * 16 + ln] = f2bf(o * gv);
        }
    }
}

// ---------------------------------------------------------------------------
extern "C" void kernel_launch(void* const* d_in, const int* in_sizes, int n_in,
                              void* d_out, int out_size, void* d_ws, size_t ws_size,
                              hipStream_t stream) {
    const float* X   = (const float*)d_in[0];
    const float* Wq  = (const float*)d_in[1];
    const float* Wk  = (const float*)d_in[2];
    const float* Wv  = (const float*)d_in[3];
    const float* Wg  = (const float*)d_in[4];
    const float* Wo  = (const float*)d_in[5];
    const float* gnw = (const float*)d_in[6];
    const float* gnb = (const float*)d_in[7];
    float* out = (float*)d_out;

    const size_t MB = 1u << 20;
    char* base = (char*)d_ws;
    // Sb (32 MB, 0-32) overlays tbl/Xb/Wq..Wg, which die after the QKVG mm.
    ushort* Sb  = (ushort*)base;                        // 0-32  (L then P, bf16)
    float4* tbl = (float4*)base;                        // 0-2
    ushort* Xb  = (ushort*)(base + 2 * MB);             // 2-18
    ushort* Wqt = (ushort*)(base + 18 * MB);
    ushort* Wkt = (ushort*)(base + 20 * MB);
    ushort* Wvt = (ushort*)(base + 22 * MB);
    ushort* Wgt = (ushort*)(base + 24 * MB);
    ushort* Wot = (ushort*)(base + 32 * MB);            // 32-34
    ushort* Qb  = (ushort*)(base + 34 * MB);            // 34-50
    ushort* Kb  = (ushort*)(base + 50 * MB);            // 50-66
    ushort* Gb  = (ushort*)(base + 66 * MB);            // 66-82
    ushort* Vt  = (ushort*)(base + 82 * MB);            // 82-98
    ushort* Ktb = (ushort*)(base + 98 * MB);            // 98-114 (dead after R1)
    ushort* Zb  = (ushort*)(base + 98 * MB);            // reuses Ktb region in R3+

    Gammas gp;
    for (int h = 0; h < 8; h++) {
        double lin = log(1.0 / 32.0) +
                     (log(1.0 / 512.0) - log(1.0 / 32.0)) * (double)h / 7.0;
        float gamma = 1.0f - expf((float)lin);
        gp.lg2[h] = log2f(gamma);
    }

    // single prep launch: xpos table + cast + all 5 weight transposes
    PrepArgs pa;
    pa.W[0] = Wq;  pa.Wt[0] = Wqt; pa.perhead[0] = 1;
    pa.W[1] = Wk;  pa.Wt[1] = Wkt; pa.perhead[1] = 1;
    pa.W[2] = Wv;  pa.Wt[2] = Wvt; pa.perhead[2] = 1;
    pa.W[3] = Wg;  pa.Wt[3] = Wgt; pa.perhead[3] = 0;
    pa.W[4] = Wo;  pa.Wt[4] = Wot; pa.perhead[4] = 0;
    prep_kernel<<<9984, 256, 0, stream>>>(X, Xb, tbl, pa);

    // fused Q/K/V/G projections; K emits row-major Kb AND transposed K~t
    MMArgs qa;
    qa.Bt[0] = Wqt; qa.Bt[1] = Wkt; qa.Bt[2] = Wvt; qa.Bt[3] = Wgt;
    qa.C[0] = Qb;   qa.C[1] = Kb;   qa.C[2] = Vt;   qa.C[3] = Gb;
    qa.C2[0] = nullptr; qa.C2[1] = Ktb; qa.C2[2] = nullptr; qa.C2[3] = nullptr;
    qa.emode[0] = 1; qa.emode[1] = 6; qa.emode[2] = 5; qa.emode[3] = 3;
    mm_kernel<<<dim3(32, 64), 256, 0, stream>>>(Xb, qa, tbl);

    // chunked-recurrent retention: local states -> scan -> per-chunk output
    state_kernel<<<dim3(32, 32), 256, 0, stream>>>(Ktb, Vt, Sb, gp);
    scan_kernel<<<dim3(8, 32), 256, 0, stream>>>(Sb, gp);
    ret2_kernel<<<dim3(32, 32), 256, 0, stream>>>(Qb, Kb, Vt, Sb, Gb,
                                                  gnw, gnb, Zb, gp);

    MMArgs oa;
    oa.Bt[0] = Wot; oa.Bt[1] = Wot; oa.Bt[2] = Wot; oa.Bt[3] = Wot;
    oa.C[0] = out;  oa.C[1] = out;  oa.C[2] = out;  oa.C[3] = out;
    oa.C2[0] = nullptr; oa.C2[1] = nullptr; oa.C2[2] = nullptr; oa.C2[3] = nullptr;
    oa.emode[0] = 4; oa.emode[1] = 4; oa.emode[2] = 4; oa.emode[3] = 4;
    mm_kernel<<<dim3(8, 64), 256, 0, stream>>>(Zb, oa, tbl);
}